// Round 14
// baseline (190.582 us; speedup 1.0000x reference)
//
#include <hip/hip_runtime.h>
#include <hip/hip_bf16.h>
#include <stdint.h>

#define NROWS 8192
#define DIM   512
#define NP    4            // 128-wide k-frags per panel (DIM/128)
#define NSTEP 4            // K-steps (BK=128)
#define FSCALE 16.0f       // fp8 pre-scale (power of 2); C is scaled by 256
#define INV_FS2 (1.0f / 256.0f)
#define SCALE1 0x7F7F7F7F  // E8M0 x1.0 in all 4 bytes

typedef unsigned char u8;
typedef float f32x4 __attribute__((ext_vector_type(4)));
typedef int i32x4 __attribute__((ext_vector_type(4)));
typedef int i32x8 __attribute__((ext_vector_type(8)));

// ---- order-preserving float<->uint encoding for atomicMax on floats ----
__device__ __forceinline__ unsigned fenc(float f) {
  unsigned u = __float_as_uint(f);
  return (u & 0x80000000u) ? ~u : (u | 0x80000000u);
}
__device__ __forceinline__ float fdec(unsigned u) {
  unsigned b = (u & 0x80000000u) ? (u ^ 0x80000000u) : ~u;
  return __uint_as_float(b);
}

// ---- f32 -> fp8 e4m3fn (OCP) ----
#if __has_builtin(__builtin_amdgcn_cvt_pk_fp8_f32)
#define HAVE_CVT_PK_FP8 1
#else
__device__ __forceinline__ u8 f2e4m3(float f) {
  unsigned u = __float_as_uint(f);
  unsigned sgn = (u >> 24) & 0x80u;
  unsigned au = u & 0x7FFFFFFFu;
  if (au < 0x3C800000u) return (u8)sgn;
  unsigned r = au + 0x7FFFFu + ((au >> 20) & 1u);
  int e = (int)((r >> 23) & 0xFF) - 127;
  unsigned m = (r >> 20) & 7u;
  if (e > 8) return (u8)(sgn | 0x7Eu);
  return (u8)(sgn | ((unsigned)(e + 7) << 3) | m);
}
#endif

__device__ __forceinline__ void async16(const void* g, void* l) {
  __builtin_amdgcn_global_load_lds(
      (const __attribute__((address_space(1))) unsigned int*)g,
      (__attribute__((address_space(3))) unsigned int*)l, 16, 0, 0);
}

// ---- normalize 16 rows (one panel) -> fp8, MX-fragment-major layout ----
// Fragment (panel P, f): 16 rows x 128 k, 2 KB at (P*NP+f)*2048 bytes,
// stored as two lane-linear 1 KB halves: operand lane l = (row&15)+16*kg
// holds k = kg*32 + j; byte j at half (j>>4), offset lane*16 + (j&15).
// blockIdx 0..511 -> ex, 512.. -> ey; first 32 blocks init max arrays.
__global__ __launch_bounds__(512) void normf_kernel(
    const float* __restrict__ ex, const float* __restrict__ ey,
    u8* __restrict__ Xf, u8* __restrict__ Yf,
    unsigned* __restrict__ enc_init) {
  const int pb = blockIdx.x;
  const int p = pb & 511;
  const float* src = (pb < 512) ? ex : ey;
  u8* dst = (pb < 512) ? Xf : Yf;
  const int t = threadIdx.x, lane = t & 63, w = t >> 6;
  const int fr = lane & 15, hi = lane >> 4;
  if (pb < 32) {
    enc_init[pb * 512 + t] = fenc(-512.0f);
  }
  __shared__ float part[16][8];
  float e[2][8];
  float ss = 0.f;
#pragma unroll
  for (int c = 0; c < 2; ++c) {
    const int q = w + c * 8;
    const float* g = src + (size_t)(p * 16 + fr) * DIM + q * 32 + hi * 8;
    float4 v0 = *(const float4*)g;
    float4 v1 = *(const float4*)(g + 4);
    e[c][0] = v0.x; e[c][1] = v0.y; e[c][2] = v0.z; e[c][3] = v0.w;
    e[c][4] = v1.x; e[c][5] = v1.y; e[c][6] = v1.z; e[c][7] = v1.w;
#pragma unroll
    for (int j = 0; j < 8; ++j) ss += e[c][j] * e[c][j];
  }
  ss += __shfl_xor(ss, 16);
  ss += __shfl_xor(ss, 32);
  if (lane < 16) part[lane][w] = ss;
  __syncthreads();
  float tot = 0.f;
#pragma unroll
  for (int i = 0; i < 8; ++i) tot += part[fr][i];
  const float sc = FSCALE / fmaxf(sqrtf(tot), 1e-8f);
#pragma unroll
  for (int c = 0; c < 2; ++c) {
    const int q = w + c * 8;  // q = global 32-wide k-group, 0..15
#if HAVE_CVT_PK_FP8
    int lo = 0, hi2 = 0;
    lo = __builtin_amdgcn_cvt_pk_fp8_f32(e[c][0] * sc, e[c][1] * sc, lo, false);
    lo = __builtin_amdgcn_cvt_pk_fp8_f32(e[c][2] * sc, e[c][3] * sc, lo, true);
    hi2 = __builtin_amdgcn_cvt_pk_fp8_f32(e[c][4] * sc, e[c][5] * sc, hi2, false);
    hi2 = __builtin_amdgcn_cvt_pk_fp8_f32(e[c][6] * sc, e[c][7] * sc, hi2, true);
    const unsigned long long pk =
        (unsigned long long)(unsigned)lo | ((unsigned long long)(unsigned)hi2 << 32);
#else
    unsigned long long pk = 0;
#pragma unroll
    for (int j = 0; j < 8; ++j)
      pk |= (unsigned long long)f2e4m3(e[c][j] * sc) << (8 * j);
#endif
    const int f = q >> 2;
    const int kg = q & 3;
    const int olane = fr + kg * 16;
    const int half = hi >> 1;
    const size_t addr = (size_t)(p * NP + f) * 2048 + half * 1024 +
                        olane * 16 + (hi & 1) * 8;
    *(unsigned long long*)(dst + addr) = pk;
  }
}

// ---- 256x256 MX-fp8 GEMM, 8 waves, double-buffered, 4-phase steps ----
// Buffer (64 KB): slots 0..15 = A panels, 16..31 = B panels; slot = 2 KB
// lane-linear fragment for K-step h. Phased schedule: staging of the next
// buffer is spread across the 4 phases; single vmcnt(0) at step boundary.
__global__ __launch_bounds__(512, 2) void gemm_max_kernel(
    const u8* __restrict__ Xf, const u8* __restrict__ Yf,
    unsigned* __restrict__ rowmax, unsigned* __restrict__ colmax) {
  __shared__ u8 lds[2][32][2048];  // 128 KB

  const int t = threadIdx.x, lane = t & 63, w = t >> 6;
  const int wr = w >> 2, wc = w & 3;  // 2x4 wave grid; wave owns 128x64 out

  // bijective XCD quadrant swizzle: 1024 blocks = 32x32 tiles of 256^2.
  // XCD owns 2048 rows x 4096 cols: A 1 MB + B 2 MB resident in its L2.
  const int raw = blockIdx.x, xcd = raw & 7, l = raw >> 3;  // l: 0..127
  const int brow = ((xcd >> 1) * 8 + (l & 7)) * 256;
  const int bcol = ((xcd & 1) * 16 + (l >> 3)) * 256;
  const int browP = brow >> 4, bcolP = bcol >> 4;

  f32x4 acc[8][4];
#pragma unroll
  for (int m = 0; m < 8; ++m)
#pragma unroll
    for (int n = 0; n < 4; ++n) acc[m][n] = (f32x4){0.f, 0.f, 0.f, 0.f};

  // staging: wave w stages A panels {w, w+8} and B panels {w, w+8};
  // 2 KB per panel-frag = 2 lane-linear async16 (halves).
  const u8* gA0 = Xf + (size_t)(browP + w) * (NP * 2048) + lane * 16;
  const u8* gA1 = Xf + (size_t)(browP + w + 8) * (NP * 2048) + lane * 16;
  const u8* gB0 = Yf + (size_t)(bcolP + w) * (NP * 2048) + lane * 16;
  const u8* gB1 = Yf + (size_t)(bcolP + w + 8) * (NP * 2048) + lane * 16;

  // prologue: stage step 0 into buffer 0
#pragma unroll
  for (int half = 0; half < 2; ++half) {
    async16(gA0 + half * 1024, &lds[0][w][half * 1024]);
    async16(gA1 + half * 1024, &lds[0][w + 8][half * 1024]);
    async16(gB0 + half * 1024, &lds[0][16 + w][half * 1024]);
    async16(gB1 + half * 1024, &lds[0][16 + w + 8][half * 1024]);
  }
  asm volatile("s_waitcnt vmcnt(0)" ::: "memory");
  __builtin_amdgcn_s_barrier();

#pragma unroll
  for (int u = 0; u < NSTEP; ++u) {
    const int s = u & 1;
    const size_t go = (size_t)(u + 1) * 2048;  // next step's frag offset
    // ---- phase 0: read all B + A m={0,1}; stage next-A half 0 ----
    i32x8 b[4];
#pragma unroll
    for (int n = 0; n < 4; ++n) {
      const u8* base = &lds[s][16 + wc * 4 + n][lane * 16];
      i32x4 lo = *(const i32x4*)(base);
      i32x4 hi = *(const i32x4*)(base + 1024);
      b[n][0] = lo[0]; b[n][1] = lo[1]; b[n][2] = lo[2]; b[n][3] = lo[3];
      b[n][4] = hi[0]; b[n][5] = hi[1]; b[n][6] = hi[2]; b[n][7] = hi[3];
    }
#pragma unroll
    for (int q = 0; q < 4; ++q) {
      // read this phase's two A fragments
      i32x8 a[2];
#pragma unroll
      for (int i = 0; i < 2; ++i) {
        const u8* base = &lds[s][wr * 8 + q * 2 + i][lane * 16];
        i32x4 lo = *(const i32x4*)(base);
        i32x4 hi = *(const i32x4*)(base + 1024);
        a[i][0] = lo[0]; a[i][1] = lo[1]; a[i][2] = lo[2]; a[i][3] = lo[3];
        a[i][4] = hi[0]; a[i][5] = hi[1]; a[i][6] = hi[2]; a[i][7] = hi[3];
      }
      // stagger next-buffer staging across phases (2 loads/phase)
      if (u < NSTEP - 1) {
        if (q == 0) {
          async16(gA0 + go, &lds[s ^ 1][w][0]);
          async16(gA1 + go, &lds[s ^ 1][w + 8][0]);
        } else if (q == 1) {
          async16(gA0 + go + 1024, &lds[s ^ 1][w][1024]);
          async16(gA1 + go + 1024, &lds[s ^ 1][w + 8][1024]);
        } else if (q == 2) {
          async16(gB0 + go, &lds[s ^ 1][16 + w][0]);
          async16(gB1 + go, &lds[s ^ 1][16 + w + 8][0]);
        } else {
          async16(gB0 + go + 1024, &lds[s ^ 1][16 + w][1024]);
          async16(gB1 + go + 1024, &lds[s ^ 1][16 + w + 8][1024]);
        }
      }
      __builtin_amdgcn_s_barrier();
      __builtin_amdgcn_s_setprio(1);
#pragma unroll
      for (int i = 0; i < 2; ++i)
#pragma unroll
        for (int n = 0; n < 4; ++n)
          acc[q * 2 + i][n] = __builtin_amdgcn_mfma_scale_f32_16x16x128_f8f6f4(
              a[i], b[n], acc[q * 2 + i][n], 0, 0, 0, SCALE1, 0, SCALE1);
      __builtin_amdgcn_s_setprio(0);
      __builtin_amdgcn_s_barrier();
    }
    // step boundary: next buffer's staging (issued >= 4 phases ago) drains
    if (u < NSTEP - 1) {
      asm volatile("s_waitcnt vmcnt(0)" ::: "memory");
      __builtin_amdgcn_s_barrier();
    }
  }

  // ---- epilogue: C/D layout col=lane&15, row=(lane>>4)*4+reg (scaled) ----
#pragma unroll
  for (int m = 0; m < 8; ++m) {
    f32x4 rm = acc[m][0];
#pragma unroll
    for (int n = 1; n < 4; ++n) {
      rm[0] = fmaxf(rm[0], acc[m][n][0]);
      rm[1] = fmaxf(rm[1], acc[m][n][1]);
      rm[2] = fmaxf(rm[2], acc[m][n][2]);
      rm[3] = fmaxf(rm[3], acc[m][n][3]);
    }
#pragma unroll
    for (int r = 0; r < 4; ++r) {
      float v = rm[r];
      v = fmaxf(v, __shfl_xor(v, 1));
      v = fmaxf(v, __shfl_xor(v, 2));
      v = fmaxf(v, __shfl_xor(v, 4));
      v = fmaxf(v, __shfl_xor(v, 8));
      if ((lane & 15) == 0) {
        const int grow = brow + wr * 128 + m * 16 + (lane >> 4) * 4 + r;
        atomicMax(rowmax + grow, fenc(v));
      }
    }
  }
#pragma unroll
  for (int n = 0; n < 4; ++n) {
    float cm = -512.0f;
#pragma unroll
    for (int m = 0; m < 8; ++m) {
      cm = fmaxf(cm, acc[m][n][0]);
      cm = fmaxf(cm, acc[m][n][1]);
      cm = fmaxf(cm, acc[m][n][2]);
      cm = fmaxf(cm, acc[m][n][3]);
    }
    cm = fmaxf(cm, __shfl_xor(cm, 16));
    cm = fmaxf(cm, __shfl_xor(cm, 32));
    if (lane < 16) {
      const int gcol = bcol + wc * 64 + n * 16 + lane;
      atomicMax(colmax + gcol, fenc(cm));
    }
  }
}

// ---- entropy: out[b] = -sum( exp(lp)*lp ), x = decoded max / FSCALE^2 ----
__global__ __launch_bounds__(256) void entropy_kernel(
    const unsigned* __restrict__ enc, float* __restrict__ out) {
  const int which = blockIdx.x;
  const unsigned* e = enc + which * NROWS;
  float s = 0.0f;
  for (int i = threadIdx.x; i < NROWS; i += 256) {
    const float x = fdec(e[i]) * INV_FS2;
    const float z = (x - 1.0f) * (1.0f / 0.3f);
    const float lp = -0.5f * z * z + 0.2850342711439819f;
    s += expf(lp) * lp;
  }
#pragma unroll
  for (int m = 1; m <= 32; m <<= 1) s += __shfl_xor(s, m);
  __shared__ float sr[4];
  if ((threadIdx.x & 63) == 0) sr[threadIdx.x >> 6] = s;
  __syncthreads();
  if (threadIdx.x == 0) out[which] = -(sr[0] + sr[1] + sr[2] + sr[3]);
}

extern "C" void kernel_launch(void* const* d_in, const int* in_sizes, int n_in,
                              void* d_out, int out_size, void* d_ws, size_t ws_size,
                              hipStream_t stream) {
  const float* ex = (const float*)d_in[0];
  const float* ey = (const float*)d_in[1];

  u8* Xf = (u8*)d_ws;                                    // 4 MB MX-fragment-major
  u8* Yf = Xf + (size_t)NROWS * DIM;                     // 4 MB
  unsigned* enc = (unsigned*)(Yf + (size_t)NROWS * DIM); // 2*8192 u32
  float* out = (float*)d_out;

  hipLaunchKernelGGL(normf_kernel, dim3(1024), dim3(512), 0, stream,
                     ex, ey, Xf, Yf, enc);
  hipLaunchKernelGGL(gemm_max_kernel, dim3(1024), dim3(512), 0, stream,
                     Xf, Yf, enc, enc + NROWS);
  hipLaunchKernelGGL(entropy_kernel, dim3(2), dim3(256), 0, stream, enc, out);
}

// Round 15
// 190.350 us; speedup vs baseline: 1.0012x; 1.0012x over previous
//
#include <hip/hip_runtime.h>
#include <hip/hip_bf16.h>
#include <stdint.h>

#define NROWS 8192
#define DIM   512
#define NP    4            // 128-wide k-frags per panel (DIM/128)
#define NSTEP 4            // K-steps (BK=128)
#define FSCALE 16.0f       // fp8 pre-scale (power of 2); C is scaled by 256
#define INV_FS2 (1.0f / 256.0f)
#define SCALE1 0x7F7F7F7F  // E8M0 x1.0 in all 4 bytes

typedef unsigned char u8;
typedef float f32x4 __attribute__((ext_vector_type(4)));
typedef int i32x4 __attribute__((ext_vector_type(4)));
typedef int i32x8 __attribute__((ext_vector_type(8)));

// ---- order-preserving float<->uint encoding for atomicMax on floats ----
__device__ __forceinline__ unsigned fenc(float f) {
  unsigned u = __float_as_uint(f);
  return (u & 0x80000000u) ? ~u : (u | 0x80000000u);
}
__device__ __forceinline__ float fdec(unsigned u) {
  unsigned b = (u & 0x80000000u) ? (u ^ 0x80000000u) : ~u;
  return __uint_as_float(b);
}

// ---- f32 -> fp8 e4m3fn (OCP) ----
#if __has_builtin(__builtin_amdgcn_cvt_pk_fp8_f32)
#define HAVE_CVT_PK_FP8 1
#else
__device__ __forceinline__ u8 f2e4m3(float f) {
  unsigned u = __float_as_uint(f);
  unsigned sgn = (u >> 24) & 0x80u;
  unsigned au = u & 0x7FFFFFFFu;
  if (au < 0x3C800000u) return (u8)sgn;
  unsigned r = au + 0x7FFFFu + ((au >> 20) & 1u);
  int e = (int)((r >> 23) & 0xFF) - 127;
  unsigned m = (r >> 20) & 7u;
  if (e > 8) return (u8)(sgn | 0x7Eu);
  return (u8)(sgn | ((unsigned)(e + 7) << 3) | m);
}
#endif

__device__ __forceinline__ void async16(const void* g, void* l) {
  __builtin_amdgcn_global_load_lds(
      (const __attribute__((address_space(1))) unsigned int*)g,
      (__attribute__((address_space(3))) unsigned int*)l, 16, 0, 0);
}

// ---- normalize 16 rows (one panel) -> fp8, MX-fragment-major layout ----
// Fragment (panel P, f): 16 rows x 128 k, 2 KB at (P*NP+f)*2048 bytes,
// stored as two lane-linear 1 KB halves: operand lane l = (row&15)+16*kg
// holds k = kg*32 + j; byte j at half (j>>4), offset lane*16 + (j&15).
// blockIdx 0..511 -> ex, 512.. -> ey; first 32 blocks init max arrays.
__global__ __launch_bounds__(512) void normf_kernel(
    const float* __restrict__ ex, const float* __restrict__ ey,
    u8* __restrict__ Xf, u8* __restrict__ Yf,
    unsigned* __restrict__ enc_init) {
  const int pb = blockIdx.x;
  const int p = pb & 511;
  const float* src = (pb < 512) ? ex : ey;
  u8* dst = (pb < 512) ? Xf : Yf;
  const int t = threadIdx.x, lane = t & 63, w = t >> 6;
  const int fr = lane & 15, hi = lane >> 4;
  if (pb < 32) {
    enc_init[pb * 512 + t] = fenc(-512.0f);
  }
  __shared__ float part[16][8];
  float e[2][8];
  float ss = 0.f;
#pragma unroll
  for (int c = 0; c < 2; ++c) {
    const int q = w + c * 8;
    const float* g = src + (size_t)(p * 16 + fr) * DIM + q * 32 + hi * 8;
    float4 v0 = *(const float4*)g;
    float4 v1 = *(const float4*)(g + 4);
    e[c][0] = v0.x; e[c][1] = v0.y; e[c][2] = v0.z; e[c][3] = v0.w;
    e[c][4] = v1.x; e[c][5] = v1.y; e[c][6] = v1.z; e[c][7] = v1.w;
#pragma unroll
    for (int j = 0; j < 8; ++j) ss += e[c][j] * e[c][j];
  }
  ss += __shfl_xor(ss, 16);
  ss += __shfl_xor(ss, 32);
  if (lane < 16) part[lane][w] = ss;
  __syncthreads();
  float tot = 0.f;
#pragma unroll
  for (int i = 0; i < 8; ++i) tot += part[fr][i];
  const float sc = FSCALE / fmaxf(sqrtf(tot), 1e-8f);
#pragma unroll
  for (int c = 0; c < 2; ++c) {
    const int q = w + c * 8;  // q = global 32-wide k-group, 0..15
#if HAVE_CVT_PK_FP8
    int lo = 0, hi2 = 0;
    lo = __builtin_amdgcn_cvt_pk_fp8_f32(e[c][0] * sc, e[c][1] * sc, lo, false);
    lo = __builtin_amdgcn_cvt_pk_fp8_f32(e[c][2] * sc, e[c][3] * sc, lo, true);
    hi2 = __builtin_amdgcn_cvt_pk_fp8_f32(e[c][4] * sc, e[c][5] * sc, hi2, false);
    hi2 = __builtin_amdgcn_cvt_pk_fp8_f32(e[c][6] * sc, e[c][7] * sc, hi2, true);
    const unsigned long long pk =
        (unsigned long long)(unsigned)lo | ((unsigned long long)(unsigned)hi2 << 32);
#else
    unsigned long long pk = 0;
#pragma unroll
    for (int j = 0; j < 8; ++j)
      pk |= (unsigned long long)f2e4m3(e[c][j] * sc) << (8 * j);
#endif
    const int f = q >> 2;
    const int kg = q & 3;
    const int olane = fr + kg * 16;
    const int half = hi >> 1;
    const size_t addr = (size_t)(p * NP + f) * 2048 + half * 1024 +
                        olane * 16 + (hi & 1) * 8;
    *(unsigned long long*)(dst + addr) = pk;
  }
}

// ---- 256x256 MX-fp8 GEMM, 8 waves, double-buffered, 4-phase steps ----
// Buffer (64 KB): slots 0..15 = A panels, 16..31 = B panels; slot = 2 KB
// lane-linear fragment for K-step h. Phased schedule: staging of the next
// buffer is spread across the 4 phases; single vmcnt(0) at step boundary.
// launch_bounds(512,1): 1 block/CU -> 256-VGPR budget, no spill (r14 bug).
__global__ __launch_bounds__(512, 1) void gemm_max_kernel(
    const u8* __restrict__ Xf, const u8* __restrict__ Yf,
    unsigned* __restrict__ rowmax, unsigned* __restrict__ colmax) {
  __shared__ u8 lds[2][32][2048];  // 128 KB

  const int t = threadIdx.x, lane = t & 63, w = t >> 6;
  const int wr = w >> 2, wc = w & 3;  // 2x4 wave grid; wave owns 128x64 out

  // bijective XCD quadrant swizzle: 1024 blocks = 32x32 tiles of 256^2.
  // XCD owns 2048 rows x 4096 cols: A 1 MB + B 2 MB resident in its L2.
  const int raw = blockIdx.x, xcd = raw & 7, l = raw >> 3;  // l: 0..127
  const int brow = ((xcd >> 1) * 8 + (l & 7)) * 256;
  const int bcol = ((xcd & 1) * 16 + (l >> 3)) * 256;
  const int browP = brow >> 4, bcolP = bcol >> 4;

  f32x4 acc[8][4];
#pragma unroll
  for (int m = 0; m < 8; ++m)
#pragma unroll
    for (int n = 0; n < 4; ++n) acc[m][n] = (f32x4){0.f, 0.f, 0.f, 0.f};

  // staging: wave w stages A panels {w, w+8} and B panels {w, w+8};
  // 2 KB per panel-frag = 2 lane-linear async16 (halves).
  const u8* gA0 = Xf + (size_t)(browP + w) * (NP * 2048) + lane * 16;
  const u8* gA1 = Xf + (size_t)(browP + w + 8) * (NP * 2048) + lane * 16;
  const u8* gB0 = Yf + (size_t)(bcolP + w) * (NP * 2048) + lane * 16;
  const u8* gB1 = Yf + (size_t)(bcolP + w + 8) * (NP * 2048) + lane * 16;

  // prologue: stage step 0 into buffer 0
#pragma unroll
  for (int half = 0; half < 2; ++half) {
    async16(gA0 + half * 1024, &lds[0][w][half * 1024]);
    async16(gA1 + half * 1024, &lds[0][w + 8][half * 1024]);
    async16(gB0 + half * 1024, &lds[0][16 + w][half * 1024]);
    async16(gB1 + half * 1024, &lds[0][16 + w + 8][half * 1024]);
  }
  asm volatile("s_waitcnt vmcnt(0)" ::: "memory");
  __builtin_amdgcn_s_barrier();

#pragma unroll
  for (int u = 0; u < NSTEP; ++u) {
    const int s = u & 1;
    const size_t go = (size_t)(u + 1) * 2048;  // next step's frag offset
    // ---- per step: 4 phases; B held in regs across phases ----
    i32x8 b[4];
#pragma unroll
    for (int n = 0; n < 4; ++n) {
      const u8* base = &lds[s][16 + wc * 4 + n][lane * 16];
      i32x4 lo = *(const i32x4*)(base);
      i32x4 hi = *(const i32x4*)(base + 1024);
      b[n][0] = lo[0]; b[n][1] = lo[1]; b[n][2] = lo[2]; b[n][3] = lo[3];
      b[n][4] = hi[0]; b[n][5] = hi[1]; b[n][6] = hi[2]; b[n][7] = hi[3];
    }
#pragma unroll
    for (int q = 0; q < 4; ++q) {
      // read this phase's two A fragments
      i32x8 a[2];
#pragma unroll
      for (int i = 0; i < 2; ++i) {
        const u8* base = &lds[s][wr * 8 + q * 2 + i][lane * 16];
        i32x4 lo = *(const i32x4*)(base);
        i32x4 hi = *(const i32x4*)(base + 1024);
        a[i][0] = lo[0]; a[i][1] = lo[1]; a[i][2] = lo[2]; a[i][3] = lo[3];
        a[i][4] = hi[0]; a[i][5] = hi[1]; a[i][6] = hi[2]; a[i][7] = hi[3];
      }
      // stagger next-buffer staging across phases (2 loads/phase)
      if (u < NSTEP - 1) {
        if (q == 0) {
          async16(gA0 + go, &lds[s ^ 1][w][0]);
          async16(gA1 + go, &lds[s ^ 1][w + 8][0]);
        } else if (q == 1) {
          async16(gA0 + go + 1024, &lds[s ^ 1][w][1024]);
          async16(gA1 + go + 1024, &lds[s ^ 1][w + 8][1024]);
        } else if (q == 2) {
          async16(gB0 + go, &lds[s ^ 1][16 + w][0]);
          async16(gB1 + go, &lds[s ^ 1][16 + w + 8][0]);
        } else {
          async16(gB0 + go + 1024, &lds[s ^ 1][16 + w][1024]);
          async16(gB1 + go + 1024, &lds[s ^ 1][16 + w + 8][1024]);
        }
      }
      __builtin_amdgcn_s_barrier();
      __builtin_amdgcn_s_setprio(1);
#pragma unroll
      for (int i = 0; i < 2; ++i)
#pragma unroll
        for (int n = 0; n < 4; ++n)
          acc[q * 2 + i][n] = __builtin_amdgcn_mfma_scale_f32_16x16x128_f8f6f4(
              a[i], b[n], acc[q * 2 + i][n], 0, 0, 0, SCALE1, 0, SCALE1);
      __builtin_amdgcn_s_setprio(0);
      __builtin_amdgcn_s_barrier();
    }
    // step boundary: next buffer's staging (issued >= 4 phases ago) drains
    if (u < NSTEP - 1) {
      asm volatile("s_waitcnt vmcnt(0)" ::: "memory");
      __builtin_amdgcn_s_barrier();
    }
  }

  // ---- epilogue: C/D layout col=lane&15, row=(lane>>4)*4+reg (scaled) ----
#pragma unroll
  for (int m = 0; m < 8; ++m) {
    f32x4 rm = acc[m][0];
#pragma unroll
    for (int n = 1; n < 4; ++n) {
      rm[0] = fmaxf(rm[0], acc[m][n][0]);
      rm[1] = fmaxf(rm[1], acc[m][n][1]);
      rm[2] = fmaxf(rm[2], acc[m][n][2]);
      rm[3] = fmaxf(rm[3], acc[m][n][3]);
    }
#pragma unroll
    for (int r = 0; r < 4; ++r) {
      float v = rm[r];
      v = fmaxf(v, __shfl_xor(v, 1));
      v = fmaxf(v, __shfl_xor(v, 2));
      v = fmaxf(v, __shfl_xor(v, 4));
      v = fmaxf(v, __shfl_xor(v, 8));
      if ((lane & 15) == 0) {
        const int grow = brow + wr * 128 + m * 16 + (lane >> 4) * 4 + r;
        atomicMax(rowmax + grow, fenc(v));
      }
    }
  }
#pragma unroll
  for (int n = 0; n < 4; ++n) {
    float cm = -512.0f;
#pragma unroll
    for (int m = 0; m < 8; ++m) {
      cm = fmaxf(cm, acc[m][n][0]);
      cm = fmaxf(cm, acc[m][n][1]);
      cm = fmaxf(cm, acc[m][n][2]);
      cm = fmaxf(cm, acc[m][n][3]);
    }
    cm = fmaxf(cm, __shfl_xor(cm, 16));
    cm = fmaxf(cm, __shfl_xor(cm, 32));
    if (lane < 16) {
      const int gcol = bcol + wc * 64 + n * 16 + lane;
      atomicMax(colmax + gcol, fenc(cm));
    }
  }
}

// ---- entropy: out[b] = -sum( exp(lp)*lp ), x = decoded max / FSCALE^2 ----
__global__ __launch_bounds__(256) void entropy_kernel(
    const unsigned* __restrict__ enc, float* __restrict__ out) {
  const int which = blockIdx.x;
  const unsigned* e = enc + which * NROWS;
  float s = 0.0f;
  for (int i = threadIdx.x; i < NROWS; i += 256) {
    const float x = fdec(e[i]) * INV_FS2;
    const float z = (x - 1.0f) * (1.0f / 0.3f);
    const float lp = -0.5f * z * z + 0.2850342711439819f;
    s += expf(lp) * lp;
  }
#pragma unroll
  for (int m = 1; m <= 32; m <<= 1) s += __shfl_xor(s, m);
  __shared__ float sr[4];
  if ((threadIdx.x & 63) == 0) sr[threadIdx.x >> 6] = s;
  __syncthreads();
  if (threadIdx.x == 0) out[which] = -(sr[0] + sr[1] + sr[2] + sr[3]);
}

extern "C" void kernel_launch(void* const* d_in, const int* in_sizes, int n_in,
                              void* d_out, int out_size, void* d_ws, size_t ws_size,
                              hipStream_t stream) {
  const float* ex = (const float*)d_in[0];
  const float* ey = (const float*)d_in[1];

  u8* Xf = (u8*)d_ws;                                    // 4 MB MX-fragment-major
  u8* Yf = Xf + (size_t)NROWS * DIM;                     // 4 MB
  unsigned* enc = (unsigned*)(Yf + (size_t)NROWS * DIM); // 2*8192 u32
  float* out = (float*)d_out;

  hipLaunchKernelGGL(normf_kernel, dim3(1024), dim3(512), 0, stream,
                     ex, ey, Xf, Yf, enc);
  hipLaunchKernelGGL(gemm_max_kernel, dim3(1024), dim3(512), 0, stream,
                     Xf, Yf, enc, enc + NROWS);
  hipLaunchKernelGGL(entropy_kernel, dim3(2), dim3(256), 0, stream, enc, out);
}

// Round 16
// 190.095 us; speedup vs baseline: 1.0026x; 1.0013x over previous
//
#include <hip/hip_runtime.h>
#include <hip/hip_bf16.h>
#include <stdint.h>

#define NROWS 8192
#define DIM   512
#define NP    4            // 128-wide k-frags per panel (DIM/128)
#define NSTEP 4            // K-steps (BK=128)
#define FSCALE 16.0f       // fp8 pre-scale (power of 2); C is scaled by 256
#define INV_FS2 (1.0f / 256.0f)
#define SCALE1 0x7F7F7F7F  // E8M0 x1.0 in all 4 bytes

typedef unsigned char u8;
typedef float f32x4 __attribute__((ext_vector_type(4)));
typedef int i32x4 __attribute__((ext_vector_type(4)));
typedef int i32x8 __attribute__((ext_vector_type(8)));

// ---- order-preserving float<->uint encoding for atomicMax on floats ----
__device__ __forceinline__ unsigned fenc(float f) {
  unsigned u = __float_as_uint(f);
  return (u & 0x80000000u) ? ~u : (u | 0x80000000u);
}
__device__ __forceinline__ float fdec(unsigned u) {
  unsigned b = (u & 0x80000000u) ? (u ^ 0x80000000u) : ~u;
  return __uint_as_float(b);
}

// ---- f32 -> fp8 e4m3fn (OCP) ----
#if __has_builtin(__builtin_amdgcn_cvt_pk_fp8_f32)
#define HAVE_CVT_PK_FP8 1
#else
__device__ __forceinline__ u8 f2e4m3(float f) {
  unsigned u = __float_as_uint(f);
  unsigned sgn = (u >> 24) & 0x80u;
  unsigned au = u & 0x7FFFFFFFu;
  if (au < 0x3C800000u) return (u8)sgn;
  unsigned r = au + 0x7FFFFu + ((au >> 20) & 1u);
  int e = (int)((r >> 23) & 0xFF) - 127;
  unsigned m = (r >> 20) & 7u;
  if (e > 8) return (u8)(sgn | 0x7Eu);
  return (u8)(sgn | ((unsigned)(e + 7) << 3) | m);
}
#endif

__device__ __forceinline__ void async16(const void* g, void* l) {
  __builtin_amdgcn_global_load_lds(
      (const __attribute__((address_space(1))) unsigned int*)g,
      (__attribute__((address_space(3))) unsigned int*)l, 16, 0, 0);
}

// ---- normalize 16 rows (one panel) -> fp8, MX-fragment-major layout ----
// Fragment (panel P, f): 16 rows x 128 k, 2 KB at (P*NP+f)*2048 bytes,
// stored as two lane-linear 1 KB halves: operand lane l = (row&15)+16*kg
// holds k = kg*32 + j; byte j at half (j>>4), offset lane*16 + (j&15).
// blockIdx 0..511 -> ex, 512.. -> ey; first 32 blocks init max arrays.
__global__ __launch_bounds__(512) void normf_kernel(
    const float* __restrict__ ex, const float* __restrict__ ey,
    u8* __restrict__ Xf, u8* __restrict__ Yf,
    unsigned* __restrict__ enc_init) {
  const int pb = blockIdx.x;
  const int p = pb & 511;
  const float* src = (pb < 512) ? ex : ey;
  u8* dst = (pb < 512) ? Xf : Yf;
  const int t = threadIdx.x, lane = t & 63, w = t >> 6;
  const int fr = lane & 15, hi = lane >> 4;
  if (pb < 32) {
    enc_init[pb * 512 + t] = fenc(-512.0f);
  }
  __shared__ float part[16][8];
  float e[2][8];
  float ss = 0.f;
#pragma unroll
  for (int c = 0; c < 2; ++c) {
    const int q = w + c * 8;
    const float* g = src + (size_t)(p * 16 + fr) * DIM + q * 32 + hi * 8;
    float4 v0 = *(const float4*)g;
    float4 v1 = *(const float4*)(g + 4);
    e[c][0] = v0.x; e[c][1] = v0.y; e[c][2] = v0.z; e[c][3] = v0.w;
    e[c][4] = v1.x; e[c][5] = v1.y; e[c][6] = v1.z; e[c][7] = v1.w;
#pragma unroll
    for (int j = 0; j < 8; ++j) ss += e[c][j] * e[c][j];
  }
  ss += __shfl_xor(ss, 16);
  ss += __shfl_xor(ss, 32);
  if (lane < 16) part[lane][w] = ss;
  __syncthreads();
  float tot = 0.f;
#pragma unroll
  for (int i = 0; i < 8; ++i) tot += part[fr][i];
  const float sc = FSCALE / fmaxf(sqrtf(tot), 1e-8f);
#pragma unroll
  for (int c = 0; c < 2; ++c) {
    const int q = w + c * 8;  // q = global 32-wide k-group, 0..15
#if HAVE_CVT_PK_FP8
    int lo = 0, hi2 = 0;
    lo = __builtin_amdgcn_cvt_pk_fp8_f32(e[c][0] * sc, e[c][1] * sc, lo, false);
    lo = __builtin_amdgcn_cvt_pk_fp8_f32(e[c][2] * sc, e[c][3] * sc, lo, true);
    hi2 = __builtin_amdgcn_cvt_pk_fp8_f32(e[c][4] * sc, e[c][5] * sc, hi2, false);
    hi2 = __builtin_amdgcn_cvt_pk_fp8_f32(e[c][6] * sc, e[c][7] * sc, hi2, true);
    const unsigned long long pk =
        (unsigned long long)(unsigned)lo | ((unsigned long long)(unsigned)hi2 << 32);
#else
    unsigned long long pk = 0;
#pragma unroll
    for (int j = 0; j < 8; ++j)
      pk |= (unsigned long long)f2e4m3(e[c][j] * sc) << (8 * j);
#endif
    const int f = q >> 2;
    const int kg = q & 3;
    const int olane = fr + kg * 16;
    const int half = hi >> 1;
    const size_t addr = (size_t)(p * NP + f) * 2048 + half * 1024 +
                        olane * 16 + (hi & 1) * 8;
    *(unsigned long long*)(dst + addr) = pk;
  }
}

// ---- 256x256 MX-fp8 GEMM, 8 waves, double-buffered, 4-phase steps ----
// Buffer (64 KB): slots 0..15 = A panels, 16..31 = B panels; slot = 2 KB
// lane-linear fragment for K-step h. Staging of the next buffer is spread
// across the 4 phases; single vmcnt(0) at the step boundary.
// amdgpu_waves_per_eu(2,2): pin exactly 2 waves/EU -> 256-reg budget
// (r14/r15 spilled: launch_bounds minimum didn't lift the 128 cap).
__global__ __attribute__((amdgpu_flat_work_group_size(512, 512)))
__attribute__((amdgpu_waves_per_eu(2, 2))) void gemm_max_kernel(
    const u8* __restrict__ Xf, const u8* __restrict__ Yf,
    unsigned* __restrict__ rowmax, unsigned* __restrict__ colmax) {
  __shared__ u8 lds[2][32][2048];  // 128 KB

  const int t = threadIdx.x, lane = t & 63, w = t >> 6;
  const int wr = w >> 2, wc = w & 3;  // 2x4 wave grid; wave owns 128x64 out

  // bijective XCD quadrant swizzle: 1024 blocks = 32x32 tiles of 256^2.
  // XCD owns 2048 rows x 4096 cols: A 1 MB + B 2 MB resident in its L2.
  const int raw = blockIdx.x, xcd = raw & 7, l = raw >> 3;  // l: 0..127
  const int brow = ((xcd >> 1) * 8 + (l & 7)) * 256;
  const int bcol = ((xcd & 1) * 16 + (l >> 3)) * 256;
  const int browP = brow >> 4, bcolP = bcol >> 4;

  f32x4 acc[8][4];
#pragma unroll
  for (int m = 0; m < 8; ++m)
#pragma unroll
    for (int n = 0; n < 4; ++n) acc[m][n] = (f32x4){0.f, 0.f, 0.f, 0.f};

  // staging: wave w stages A panels {w, w+8} and B panels {w, w+8};
  // 2 KB per panel-frag = 2 lane-linear async16 (halves).
  const u8* gA0 = Xf + (size_t)(browP + w) * (NP * 2048) + lane * 16;
  const u8* gA1 = Xf + (size_t)(browP + w + 8) * (NP * 2048) + lane * 16;
  const u8* gB0 = Yf + (size_t)(bcolP + w) * (NP * 2048) + lane * 16;
  const u8* gB1 = Yf + (size_t)(bcolP + w + 8) * (NP * 2048) + lane * 16;

  // prologue: stage step 0 into buffer 0
#pragma unroll
  for (int half = 0; half < 2; ++half) {
    async16(gA0 + half * 1024, &lds[0][w][half * 1024]);
    async16(gA1 + half * 1024, &lds[0][w + 8][half * 1024]);
    async16(gB0 + half * 1024, &lds[0][16 + w][half * 1024]);
    async16(gB1 + half * 1024, &lds[0][16 + w + 8][half * 1024]);
  }
  asm volatile("s_waitcnt vmcnt(0)" ::: "memory");
  __builtin_amdgcn_s_barrier();

#pragma unroll
  for (int u = 0; u < NSTEP; ++u) {
    const int s = u & 1;
    const size_t go = (size_t)(u + 1) * 2048;  // next step's frag offset
    // ---- per step: 4 phases; B held in regs across phases ----
    i32x8 b[4];
#pragma unroll
    for (int n = 0; n < 4; ++n) {
      const u8* base = &lds[s][16 + wc * 4 + n][lane * 16];
      i32x4 lo = *(const i32x4*)(base);
      i32x4 hi = *(const i32x4*)(base + 1024);
      b[n][0] = lo[0]; b[n][1] = lo[1]; b[n][2] = lo[2]; b[n][3] = lo[3];
      b[n][4] = hi[0]; b[n][5] = hi[1]; b[n][6] = hi[2]; b[n][7] = hi[3];
    }
#pragma unroll
    for (int q = 0; q < 4; ++q) {
      // read this phase's two A fragments
      i32x8 a[2];
#pragma unroll
      for (int i = 0; i < 2; ++i) {
        const u8* base = &lds[s][wr * 8 + q * 2 + i][lane * 16];
        i32x4 lo = *(const i32x4*)(base);
        i32x4 hi = *(const i32x4*)(base + 1024);
        a[i][0] = lo[0]; a[i][1] = lo[1]; a[i][2] = lo[2]; a[i][3] = lo[3];
        a[i][4] = hi[0]; a[i][5] = hi[1]; a[i][6] = hi[2]; a[i][7] = hi[3];
      }
      // stagger next-buffer staging across phases (2 loads/phase)
      if (u < NSTEP - 1) {
        if (q == 0) {
          async16(gA0 + go, &lds[s ^ 1][w][0]);
          async16(gA1 + go, &lds[s ^ 1][w + 8][0]);
        } else if (q == 1) {
          async16(gA0 + go + 1024, &lds[s ^ 1][w][1024]);
          async16(gA1 + go + 1024, &lds[s ^ 1][w + 8][1024]);
        } else if (q == 2) {
          async16(gB0 + go, &lds[s ^ 1][16 + w][0]);
          async16(gB1 + go, &lds[s ^ 1][16 + w + 8][0]);
        } else {
          async16(gB0 + go + 1024, &lds[s ^ 1][16 + w][1024]);
          async16(gB1 + go + 1024, &lds[s ^ 1][16 + w + 8][1024]);
        }
      }
      __builtin_amdgcn_s_barrier();
      __builtin_amdgcn_s_setprio(1);
#pragma unroll
      for (int i = 0; i < 2; ++i)
#pragma unroll
        for (int n = 0; n < 4; ++n)
          acc[q * 2 + i][n] = __builtin_amdgcn_mfma_scale_f32_16x16x128_f8f6f4(
              a[i], b[n], acc[q * 2 + i][n], 0, 0, 0, SCALE1, 0, SCALE1);
      __builtin_amdgcn_s_setprio(0);
      __builtin_amdgcn_s_barrier();
    }
    // step boundary: next buffer's staging (issued >= 4 phases ago) drains
    if (u < NSTEP - 1) {
      asm volatile("s_waitcnt vmcnt(0)" ::: "memory");
      __builtin_amdgcn_s_barrier();
    }
  }

  // ---- epilogue: C/D layout col=lane&15, row=(lane>>4)*4+reg (scaled) ----
#pragma unroll
  for (int m = 0; m < 8; ++m) {
    f32x4 rm = acc[m][0];
#pragma unroll
    for (int n = 1; n < 4; ++n) {
      rm[0] = fmaxf(rm[0], acc[m][n][0]);
      rm[1] = fmaxf(rm[1], acc[m][n][1]);
      rm[2] = fmaxf(rm[2], acc[m][n][2]);
      rm[3] = fmaxf(rm[3], acc[m][n][3]);
    }
#pragma unroll
    for (int r = 0; r < 4; ++r) {
      float v = rm[r];
      v = fmaxf(v, __shfl_xor(v, 1));
      v = fmaxf(v, __shfl_xor(v, 2));
      v = fmaxf(v, __shfl_xor(v, 4));
      v = fmaxf(v, __shfl_xor(v, 8));
      if ((lane & 15) == 0) {
        const int grow = brow + wr * 128 + m * 16 + (lane >> 4) * 4 + r;
        atomicMax(rowmax + grow, fenc(v));
      }
    }
  }
#pragma unroll
  for (int n = 0; n < 4; ++n) {
    float cm = -512.0f;
#pragma unroll
    for (int m = 0; m < 8; ++m) {
      cm = fmaxf(cm, acc[m][n][0]);
      cm = fmaxf(cm, acc[m][n][1]);
      cm = fmaxf(cm, acc[m][n][2]);
      cm = fmaxf(cm, acc[m][n][3]);
    }
    cm = fmaxf(cm, __shfl_xor(cm, 16));
    cm = fmaxf(cm, __shfl_xor(cm, 32));
    if (lane < 16) {
      const int gcol = bcol + wc * 64 + n * 16 + lane;
      atomicMax(colmax + gcol, fenc(cm));
    }
  }
}

// ---- entropy: out[b] = -sum( exp(lp)*lp ), x = decoded max / FSCALE^2 ----
__global__ __launch_bounds__(256) void entropy_kernel(
    const unsigned* __restrict__ enc, float* __restrict__ out) {
  const int which = blockIdx.x;
  const unsigned* e = enc + which * NROWS;
  float s = 0.0f;
  for (int i = threadIdx.x; i < NROWS; i += 256) {
    const float x = fdec(e[i]) * INV_FS2;
    const float z = (x - 1.0f) * (1.0f / 0.3f);
    const float lp = -0.5f * z * z + 0.2850342711439819f;
    s += expf(lp) * lp;
  }
#pragma unroll
  for (int m = 1; m <= 32; m <<= 1) s += __shfl_xor(s, m);
  __shared__ float sr[4];
  if ((threadIdx.x & 63) == 0) sr[threadIdx.x >> 6] = s;
  __syncthreads();
  if (threadIdx.x == 0) out[which] = -(sr[0] + sr[1] + sr[2] + sr[3]);
}

extern "C" void kernel_launch(void* const* d_in, const int* in_sizes, int n_in,
                              void* d_out, int out_size, void* d_ws, size_t ws_size,
                              hipStream_t stream) {
  const float* ex = (const float*)d_in[0];
  const float* ey = (const float*)d_in[1];

  u8* Xf = (u8*)d_ws;                                    // 4 MB MX-fragment-major
  u8* Yf = Xf + (size_t)NROWS * DIM;                     // 4 MB
  unsigned* enc = (unsigned*)(Yf + (size_t)NROWS * DIM); // 2*8192 u32
  float* out = (float*)d_out;

  hipLaunchKernelGGL(normf_kernel, dim3(1024), dim3(512), 0, stream,
                     ex, ey, Xf, Yf, enc);
  hipLaunchKernelGGL(gemm_max_kernel, dim3(1024), dim3(512), 0, stream,
                     Xf, Yf, enc, enc + NROWS);
  hipLaunchKernelGGL(entropy_kernel, dim3(2), dim3(256), 0, stream, enc, out);
}

// Round 17
// 78.366 us; speedup vs baseline: 2.4319x; 2.4257x over previous
//
#include <hip/hip_runtime.h>
#include <hip/hip_bf16.h>
#include <stdint.h>

#define NROWS 8192
#define DIM   512
#define NP    4            // 128-wide k-frags per panel (DIM/128)
#define NSTEP 4            // K-steps per tile (BK=128)
#define NTILE 4            // output tiles per block (same brow, 4 bcols)
#define FSCALE 16.0f       // fp8 pre-scale (power of 2); C is scaled by 256
#define INV_FS2 (1.0f / 256.0f)
#define SCALE1 0x7F7F7F7F  // E8M0 x1.0 in all 4 bytes

typedef unsigned char u8;
typedef float f32x4 __attribute__((ext_vector_type(4)));
typedef int i32x4 __attribute__((ext_vector_type(4)));
typedef int i32x8 __attribute__((ext_vector_type(8)));

// ---- order-preserving float<->uint encoding for atomicMax on floats ----
__device__ __forceinline__ unsigned fenc(float f) {
  unsigned u = __float_as_uint(f);
  return (u & 0x80000000u) ? ~u : (u | 0x80000000u);
}
__device__ __forceinline__ float fdec(unsigned u) {
  unsigned b = (u & 0x80000000u) ? (u ^ 0x80000000u) : ~u;
  return __uint_as_float(b);
}

// ---- f32 -> fp8 e4m3fn (OCP) ----
#if __has_builtin(__builtin_amdgcn_cvt_pk_fp8_f32)
#define HAVE_CVT_PK_FP8 1
#else
__device__ __forceinline__ u8 f2e4m3(float f) {
  unsigned u = __float_as_uint(f);
  unsigned sgn = (u >> 24) & 0x80u;
  unsigned au = u & 0x7FFFFFFFu;
  if (au < 0x3C800000u) return (u8)sgn;
  unsigned r = au + 0x7FFFFu + ((au >> 20) & 1u);
  int e = (int)((r >> 23) & 0xFF) - 127;
  unsigned m = (r >> 20) & 7u;
  if (e > 8) return (u8)(sgn | 0x7Eu);
  return (u8)(sgn | ((unsigned)(e + 7) << 3) | m);
}
#endif

__device__ __forceinline__ void async16(const void* g, void* l) {
  __builtin_amdgcn_global_load_lds(
      (const __attribute__((address_space(1))) unsigned int*)g,
      (__attribute__((address_space(3))) unsigned int*)l, 16, 0, 0);
}

// ---- normalize 16 rows (one panel) -> fp8, MX-fragment-major layout ----
// Fragment (panel P, f): 16 rows x 128 k, 2 KB at (P*NP+f)*2048 bytes,
// stored as two lane-linear 1 KB halves: operand lane l = (row&15)+16*kg
// holds k = kg*32 + j; byte j at half (j>>4), offset lane*16 + (j&15).
// blockIdx 0..511 -> ex, 512.. -> ey; first 32 blocks init max arrays.
__global__ __launch_bounds__(512) void normf_kernel(
    const float* __restrict__ ex, const float* __restrict__ ey,
    u8* __restrict__ Xf, u8* __restrict__ Yf,
    unsigned* __restrict__ enc_init) {
  const int pb = blockIdx.x;
  const int p = pb & 511;
  const float* src = (pb < 512) ? ex : ey;
  u8* dst = (pb < 512) ? Xf : Yf;
  const int t = threadIdx.x, lane = t & 63, w = t >> 6;
  const int fr = lane & 15, hi = lane >> 4;
  if (pb < 32) {
    enc_init[pb * 512 + t] = fenc(-512.0f);
  }
  __shared__ float part[16][8];
  float e[2][8];
  float ss = 0.f;
#pragma unroll
  for (int c = 0; c < 2; ++c) {
    const int q = w + c * 8;
    const float* g = src + (size_t)(p * 16 + fr) * DIM + q * 32 + hi * 8;
    float4 v0 = *(const float4*)g;
    float4 v1 = *(const float4*)(g + 4);
    e[c][0] = v0.x; e[c][1] = v0.y; e[c][2] = v0.z; e[c][3] = v0.w;
    e[c][4] = v1.x; e[c][5] = v1.y; e[c][6] = v1.z; e[c][7] = v1.w;
#pragma unroll
    for (int j = 0; j < 8; ++j) ss += e[c][j] * e[c][j];
  }
  ss += __shfl_xor(ss, 16);
  ss += __shfl_xor(ss, 32);
  if (lane < 16) part[lane][w] = ss;
  __syncthreads();
  float tot = 0.f;
#pragma unroll
  for (int i = 0; i < 8; ++i) tot += part[fr][i];
  const float sc = FSCALE / fmaxf(sqrtf(tot), 1e-8f);
#pragma unroll
  for (int c = 0; c < 2; ++c) {
    const int q = w + c * 8;  // q = global 32-wide k-group, 0..15
#if HAVE_CVT_PK_FP8
    int lo = 0, hi2 = 0;
    lo = __builtin_amdgcn_cvt_pk_fp8_f32(e[c][0] * sc, e[c][1] * sc, lo, false);
    lo = __builtin_amdgcn_cvt_pk_fp8_f32(e[c][2] * sc, e[c][3] * sc, lo, true);
    hi2 = __builtin_amdgcn_cvt_pk_fp8_f32(e[c][4] * sc, e[c][5] * sc, hi2, false);
    hi2 = __builtin_amdgcn_cvt_pk_fp8_f32(e[c][6] * sc, e[c][7] * sc, hi2, true);
    const unsigned long long pk =
        (unsigned long long)(unsigned)lo | ((unsigned long long)(unsigned)hi2 << 32);
#else
    unsigned long long pk = 0;
#pragma unroll
    for (int j = 0; j < 8; ++j)
      pk |= (unsigned long long)f2e4m3(e[c][j] * sc) << (8 * j);
#endif
    const int f = q >> 2;
    const int kg = q & 3;
    const int olane = fr + kg * 16;
    const int half = hi >> 1;
    const size_t addr = (size_t)(p * NP + f) * 2048 + half * 1024 +
                        olane * 16 + (hi & 1) * 8;
    *(unsigned long long*)(dst + addr) = pk;
  }
}

// ---- 128x128 MX-fp8 GEMM, single 32 KB buffer, 4 tiles per block ----
// LDS: A frags 0..7 (panels), B frags 8..15; frag = 2 KB lane-linear.
__global__ __launch_bounds__(256, 3) void gemm_max_kernel(
    const u8* __restrict__ Xf, const u8* __restrict__ Yf,
    unsigned* __restrict__ rowmax, unsigned* __restrict__ colmax) {
  __shared__ u8 lds[16][2048];  // 32 KB

  const int t = threadIdx.x, lane = t & 63, w = t >> 6;
  const int wr = w >> 1, wc = w & 1;  // 2x2 wave grid; wave owns 64x64 out

  // L2-locality swizzle: XCD x owns a 2048-row x 4096-col quadrant
  // (16 brows x 8 stripes): A 1 MB + B 2 MB fits the 4 MB per-XCD L2.
  const int raw = blockIdx.x, xcd = raw & 7, l = raw >> 3;  // l: 0..127
  const int brow = ((xcd >> 1) * 16 + (l & 15)) * 128;
  const int bcol0 = ((xcd & 1) * 8 + (l >> 4)) * 512;  // base of 4 tiles
  const int browP = brow >> 4;

  f32x4 acc[4][4];
#pragma unroll
  for (int m = 0; m < 4; ++m)
#pragma unroll
    for (int n = 0; n < 4; ++n) acc[m][n] = (f32x4){0.f, 0.f, 0.f, 0.f};

  // A staging sources are fixed for the whole block.
  const u8* gA0 = Xf + (size_t)(browP + 2 * w) * (NP * 2048) + lane * 16;
  const u8* gA1 = Xf + (size_t)(browP + 2 * w + 1) * (NP * 2048) + lane * 16;
  // B base for the 512-col stripe; per unit u we add tile/panel offsets.
  const u8* gBb = Yf + (size_t)(bcol0 >> 4) * (NP * 2048) + lane * 16;

  // continuous 16-step loop: u = tile*4 + h
#pragma unroll 1
  for (int u = 0; u < NTILE * NSTEP; ++u) {
    const int h = u & 3;
    const int tileP = (u >> 2) * 8;  // panel offset of this tile's bcol
    const size_t o = (size_t)h * 2048;
    __syncthreads();  // previous compute done -> buffer reusable
    {
      const u8* gB0 = gBb + (size_t)(tileP + 2 * w) * (NP * 2048);
      const u8* gB1 = gBb + (size_t)(tileP + 2 * w + 1) * (NP * 2048);
#pragma unroll
      for (int half = 0; half < 2; ++half) {
        async16(gA0 + o + half * 1024, &lds[2 * w][half * 1024]);
        async16(gA1 + o + half * 1024, &lds[2 * w + 1][half * 1024]);
        async16(gB0 + o + half * 1024, &lds[8 + 2 * w][half * 1024]);
        async16(gB1 + o + half * 1024, &lds[8 + 2 * w + 1][half * 1024]);
      }
    }
    __syncthreads();  // compiler drains vmcnt before barrier -> data ready
    i32x8 b[4];
#pragma unroll
    for (int n = 0; n < 4; ++n) {
      const u8* base = &lds[8 + wc * 4 + n][0];
      i32x4 lo = *(const i32x4*)(base + lane * 16);
      i32x4 hi = *(const i32x4*)(base + 1024 + lane * 16);
      b[n][0] = lo[0]; b[n][1] = lo[1]; b[n][2] = lo[2]; b[n][3] = lo[3];
      b[n][4] = hi[0]; b[n][5] = hi[1]; b[n][6] = hi[2]; b[n][7] = hi[3];
    }
#pragma unroll
    for (int m = 0; m < 4; ++m) {
      const u8* base = &lds[wr * 4 + m][0];
      i32x4 lo = *(const i32x4*)(base + lane * 16);
      i32x4 hi = *(const i32x4*)(base + 1024 + lane * 16);
      i32x8 a;
      a[0] = lo[0]; a[1] = lo[1]; a[2] = lo[2]; a[3] = lo[3];
      a[4] = hi[0]; a[5] = hi[1]; a[6] = hi[2]; a[7] = hi[3];
#pragma unroll
      for (int n = 0; n < 4; ++n)
        acc[m][n] = __builtin_amdgcn_mfma_scale_f32_16x16x128_f8f6f4(
            a, b[n], acc[m][n], 0, 0, 0, SCALE1, 0, SCALE1);
    }

    if (h == 3) {  // tile finished: fused max epilogue, then rezero acc
      const int bcol = bcol0 + (u >> 2) * 128;
#pragma unroll
      for (int m = 0; m < 4; ++m) {
        f32x4 rm = acc[m][0];
#pragma unroll
        for (int n = 1; n < 4; ++n) {
          rm[0] = fmaxf(rm[0], acc[m][n][0]);
          rm[1] = fmaxf(rm[1], acc[m][n][1]);
          rm[2] = fmaxf(rm[2], acc[m][n][2]);
          rm[3] = fmaxf(rm[3], acc[m][n][3]);
        }
#pragma unroll
        for (int r = 0; r < 4; ++r) {
          float v = rm[r];
          v = fmaxf(v, __shfl_xor(v, 1));
          v = fmaxf(v, __shfl_xor(v, 2));
          v = fmaxf(v, __shfl_xor(v, 4));
          v = fmaxf(v, __shfl_xor(v, 8));
          if ((lane & 15) == 0) {
            const int grow = brow + wr * 64 + m * 16 + (lane >> 4) * 4 + r;
            atomicMax(rowmax + grow, fenc(v));
          }
        }
      }
#pragma unroll
      for (int n = 0; n < 4; ++n) {
        float cm = -512.0f;
#pragma unroll
        for (int m = 0; m < 4; ++m) {
          cm = fmaxf(cm, acc[m][n][0]);
          cm = fmaxf(cm, acc[m][n][1]);
          cm = fmaxf(cm, acc[m][n][2]);
          cm = fmaxf(cm, acc[m][n][3]);
        }
        cm = fmaxf(cm, __shfl_xor(cm, 16));
        cm = fmaxf(cm, __shfl_xor(cm, 32));
        if (lane < 16) {
          const int gcol = bcol + wc * 64 + n * 16 + lane;
          atomicMax(colmax + gcol, fenc(cm));
        }
      }
#pragma unroll
      for (int m = 0; m < 4; ++m)
#pragma unroll
        for (int n = 0; n < 4; ++n) acc[m][n] = (f32x4){0.f, 0.f, 0.f, 0.f};
    }
  }
}

// ---- entropy: out[b] = -sum( exp(lp)*lp ), x = decoded max / FSCALE^2 ----
__global__ __launch_bounds__(256) void entropy_kernel(
    const unsigned* __restrict__ enc, float* __restrict__ out) {
  const int which = blockIdx.x;
  const unsigned* e = enc + which * NROWS;
  float s = 0.0f;
  for (int i = threadIdx.x; i < NROWS; i += 256) {
    const float x = fdec(e[i]) * INV_FS2;
    const float z = (x - 1.0f) * (1.0f / 0.3f);
    const float lp = -0.5f * z * z + 0.2850342711439819f;
    s += expf(lp) * lp;
  }
#pragma unroll
  for (int m = 1; m <= 32; m <<= 1) s += __shfl_xor(s, m);
  __shared__ float sr[4];
  if ((threadIdx.x & 63) == 0) sr[threadIdx.x >> 6] = s;
  __syncthreads();
  if (threadIdx.x == 0) out[which] = -(sr[0] + sr[1] + sr[2] + sr[3]);
}

extern "C" void kernel_launch(void* const* d_in, const int* in_sizes, int n_in,
                              void* d_out, int out_size, void* d_ws, size_t ws_size,
                              hipStream_t stream) {
  const float* ex = (const float*)d_in[0];
  const float* ey = (const float*)d_in[1];

  u8* Xf = (u8*)d_ws;                                    // 4 MB MX-fragment-major
  u8* Yf = Xf + (size_t)NROWS * DIM;                     // 4 MB
  unsigned* enc = (unsigned*)(Yf + (size_t)NROWS * DIM); // 2*8192 u32
  float* out = (float*)d_out;

  hipLaunchKernelGGL(normf_kernel, dim3(1024), dim3(512), 0, stream,
                     ex, ey, Xf, Yf, enc);
  hipLaunchKernelGGL(gemm_max_kernel, dim3(1024), dim3(256), 0, stream,
                     Xf, Yf, enc, enc + NROWS);
  hipLaunchKernelGGL(entropy_kernel, dim3(2), dim3(256), 0, stream, enc, out);
}

// Round 18
// 69.322 us; speedup vs baseline: 2.7492x; 1.1305x over previous
//
#include <hip/hip_runtime.h>
#include <hip/hip_bf16.h>
#include <stdint.h>

#define NROWS 8192
#define DIM   512
#define NP    4            // 128-wide k-frags per panel (DIM/128)
#define NSTEP 4            // K-steps per tile (BK=128)
#define NTILE 4            // output tiles per block (same brow, 4 bcols)
#define FSCALE 16.0f       // fp8 pre-scale (power of 2); C is scaled by 256
#define INV_FS2 (1.0f / 256.0f)
#define SCALE1 0x7F7F7F7F  // E8M0 x1.0 in all 4 bytes

typedef unsigned char u8;
typedef float f32x4 __attribute__((ext_vector_type(4)));
typedef int i32x4 __attribute__((ext_vector_type(4)));
typedef int i32x8 __attribute__((ext_vector_type(8)));

// ---- order-preserving float<->uint encoding for atomicMax on floats ----
__device__ __forceinline__ unsigned fenc(float f) {
  unsigned u = __float_as_uint(f);
  return (u & 0x80000000u) ? ~u : (u | 0x80000000u);
}
__device__ __forceinline__ float fdec(unsigned u) {
  unsigned b = (u & 0x80000000u) ? (u ^ 0x80000000u) : ~u;
  return __uint_as_float(b);
}

// ---- f32 -> fp8 e4m3fn (OCP) ----
#if __has_builtin(__builtin_amdgcn_cvt_pk_fp8_f32)
#define HAVE_CVT_PK_FP8 1
#else
__device__ __forceinline__ u8 f2e4m3(float f) {
  unsigned u = __float_as_uint(f);
  unsigned sgn = (u >> 24) & 0x80u;
  unsigned au = u & 0x7FFFFFFFu;
  if (au < 0x3C800000u) return (u8)sgn;
  unsigned r = au + 0x7FFFFu + ((au >> 20) & 1u);
  int e = (int)((r >> 23) & 0xFF) - 127;
  unsigned m = (r >> 20) & 7u;
  if (e > 8) return (u8)(sgn | 0x7Eu);
  return (u8)(sgn | ((unsigned)(e + 7) << 3) | m);
}
#endif

__device__ __forceinline__ void async16(const void* g, void* l) {
  __builtin_amdgcn_global_load_lds(
      (const __attribute__((address_space(1))) unsigned int*)g,
      (__attribute__((address_space(3))) unsigned int*)l, 16, 0, 0);
}

// ---- normalize 16 rows (one panel) -> fp8, MX-fragment-major layout ----
// Fragment (panel P, f): 16 rows x 128 k, 2 KB at (P*NP+f)*2048 bytes,
// stored as two lane-linear 1 KB halves: operand lane l = (row&15)+16*kg
// holds k = kg*32 + j; byte j at half (j>>4), offset lane*16 + (j&15).
// blockIdx 0..511 -> ex, 512.. -> ey; first 32 blocks init max arrays.
__global__ __launch_bounds__(512) void normf_kernel(
    const float* __restrict__ ex, const float* __restrict__ ey,
    u8* __restrict__ Xf, u8* __restrict__ Yf,
    unsigned* __restrict__ enc_init) {
  const int pb = blockIdx.x;
  const int p = pb & 511;
  const float* src = (pb < 512) ? ex : ey;
  u8* dst = (pb < 512) ? Xf : Yf;
  const int t = threadIdx.x, lane = t & 63, w = t >> 6;
  const int fr = lane & 15, hi = lane >> 4;
  if (pb < 32) {
    enc_init[pb * 512 + t] = fenc(-512.0f);
  }
  __shared__ float part[16][8];
  float e[2][8];
  float ss = 0.f;
#pragma unroll
  for (int c = 0; c < 2; ++c) {
    const int q = w + c * 8;
    const float* g = src + (size_t)(p * 16 + fr) * DIM + q * 32 + hi * 8;
    float4 v0 = *(const float4*)g;
    float4 v1 = *(const float4*)(g + 4);
    e[c][0] = v0.x; e[c][1] = v0.y; e[c][2] = v0.z; e[c][3] = v0.w;
    e[c][4] = v1.x; e[c][5] = v1.y; e[c][6] = v1.z; e[c][7] = v1.w;
#pragma unroll
    for (int j = 0; j < 8; ++j) ss += e[c][j] * e[c][j];
  }
  ss += __shfl_xor(ss, 16);
  ss += __shfl_xor(ss, 32);
  if (lane < 16) part[lane][w] = ss;
  __syncthreads();
  float tot = 0.f;
#pragma unroll
  for (int i = 0; i < 8; ++i) tot += part[fr][i];
  const float sc = FSCALE / fmaxf(sqrtf(tot), 1e-8f);
#pragma unroll
  for (int c = 0; c < 2; ++c) {
    const int q = w + c * 8;  // q = global 32-wide k-group, 0..15
#if HAVE_CVT_PK_FP8
    int lo = 0, hi2 = 0;
    lo = __builtin_amdgcn_cvt_pk_fp8_f32(e[c][0] * sc, e[c][1] * sc, lo, false);
    lo = __builtin_amdgcn_cvt_pk_fp8_f32(e[c][2] * sc, e[c][3] * sc, lo, true);
    hi2 = __builtin_amdgcn_cvt_pk_fp8_f32(e[c][4] * sc, e[c][5] * sc, hi2, false);
    hi2 = __builtin_amdgcn_cvt_pk_fp8_f32(e[c][6] * sc, e[c][7] * sc, hi2, true);
    const unsigned long long pk =
        (unsigned long long)(unsigned)lo | ((unsigned long long)(unsigned)hi2 << 32);
#else
    unsigned long long pk = 0;
#pragma unroll
    for (int j = 0; j < 8; ++j)
      pk |= (unsigned long long)f2e4m3(e[c][j] * sc) << (8 * j);
#endif
    const int f = q >> 2;
    const int kg = q & 3;
    const int olane = fr + kg * 16;
    const int half = hi >> 1;
    const size_t addr = (size_t)(p * NP + f) * 2048 + half * 1024 +
                        olane * 16 + (hi & 1) * 8;
    *(unsigned long long*)(dst + addr) = pk;
  }
}

// ---- 128x128 MX-fp8 GEMM, single 32 KB buffer, 4 tiles per block ----
// LDS: A frags 0..7 (panels), B frags 8..15; frag = 2 KB lane-linear.
__global__ __launch_bounds__(256, 3) void gemm_max_kernel(
    const u8* __restrict__ Xf, const u8* __restrict__ Yf,
    unsigned* __restrict__ rowmax, unsigned* __restrict__ colmax) {
  __shared__ u8 lds[16][2048];  // 32 KB

  const int t = threadIdx.x, lane = t & 63, w = t >> 6;
  const int wr = w >> 1, wc = w & 1;  // 2x2 wave grid; wave owns 64x64 out

  // L2-locality swizzle: XCD x owns a 2048-row x 4096-col quadrant
  // (16 brows x 8 stripes): A 1 MB + B 2 MB fits the 4 MB per-XCD L2.
  const int raw = blockIdx.x, xcd = raw & 7, l = raw >> 3;  // l: 0..127
  const int brow = ((xcd >> 1) * 16 + (l & 15)) * 128;
  const int bcol0 = ((xcd & 1) * 8 + (l >> 4)) * 512;  // base of 4 tiles
  const int browP = brow >> 4;

  f32x4 acc[4][4];
#pragma unroll
  for (int m = 0; m < 4; ++m)
#pragma unroll
    for (int n = 0; n < 4; ++n) acc[m][n] = (f32x4){0.f, 0.f, 0.f, 0.f};

  // A staging sources are fixed for the whole block.
  const u8* gA0 = Xf + (size_t)(browP + 2 * w) * (NP * 2048) + lane * 16;
  const u8* gA1 = Xf + (size_t)(browP + 2 * w + 1) * (NP * 2048) + lane * 16;
  // B base for the 512-col stripe; per unit u we add tile/panel offsets.
  const u8* gBb = Yf + (size_t)(bcol0 >> 4) * (NP * 2048) + lane * 16;

  // continuous 16-step loop: u = tile*4 + h
#pragma unroll 1
  for (int u = 0; u < NTILE * NSTEP; ++u) {
    const int h = u & 3;
    const int tileP = (u >> 2) * 8;  // panel offset of this tile's bcol
    const size_t o = (size_t)h * 2048;
    __syncthreads();  // previous compute done -> buffer reusable
    {
      const u8* gB0 = gBb + (size_t)(tileP + 2 * w) * (NP * 2048);
      const u8* gB1 = gBb + (size_t)(tileP + 2 * w + 1) * (NP * 2048);
#pragma unroll
      for (int half = 0; half < 2; ++half) {
        async16(gA0 + o + half * 1024, &lds[2 * w][half * 1024]);
        async16(gA1 + o + half * 1024, &lds[2 * w + 1][half * 1024]);
        async16(gB0 + o + half * 1024, &lds[8 + 2 * w][half * 1024]);
        async16(gB1 + o + half * 1024, &lds[8 + 2 * w + 1][half * 1024]);
      }
    }
    __syncthreads();  // compiler drains vmcnt before barrier -> data ready
    i32x8 b[4];
#pragma unroll
    for (int n = 0; n < 4; ++n) {
      const u8* base = &lds[8 + wc * 4 + n][0];
      i32x4 lo = *(const i32x4*)(base + lane * 16);
      i32x4 hi = *(const i32x4*)(base + 1024 + lane * 16);
      b[n][0] = lo[0]; b[n][1] = lo[1]; b[n][2] = lo[2]; b[n][3] = lo[3];
      b[n][4] = hi[0]; b[n][5] = hi[1]; b[n][6] = hi[2]; b[n][7] = hi[3];
    }
#pragma unroll
    for (int m = 0; m < 4; ++m) {
      const u8* base = &lds[wr * 4 + m][0];
      i32x4 lo = *(const i32x4*)(base + lane * 16);
      i32x4 hi = *(const i32x4*)(base + 1024 + lane * 16);
      i32x8 a;
      a[0] = lo[0]; a[1] = lo[1]; a[2] = lo[2]; a[3] = lo[3];
      a[4] = hi[0]; a[5] = hi[1]; a[6] = hi[2]; a[7] = hi[3];
#pragma unroll
      for (int n = 0; n < 4; ++n)
        acc[m][n] = __builtin_amdgcn_mfma_scale_f32_16x16x128_f8f6f4(
            a, b[n], acc[m][n], 0, 0, 0, SCALE1, 0, SCALE1);
    }

    if (h == 3) {  // tile finished: fused max epilogue, then rezero acc
      const int bcol = bcol0 + (u >> 2) * 128;
#pragma unroll
      for (int m = 0; m < 4; ++m) {
        f32x4 rm = acc[m][0];
#pragma unroll
        for (int n = 1; n < 4; ++n) {
          rm[0] = fmaxf(rm[0], acc[m][n][0]);
          rm[1] = fmaxf(rm[1], acc[m][n][1]);
          rm[2] = fmaxf(rm[2], acc[m][n][2]);
          rm[3] = fmaxf(rm[3], acc[m][n][3]);
        }
#pragma unroll
        for (int r = 0; r < 4; ++r) {
          float v = rm[r];
          v = fmaxf(v, __shfl_xor(v, 1));
          v = fmaxf(v, __shfl_xor(v, 2));
          v = fmaxf(v, __shfl_xor(v, 4));
          v = fmaxf(v, __shfl_xor(v, 8));
          if ((lane & 15) == 0) {
            const int grow = brow + wr * 64 + m * 16 + (lane >> 4) * 4 + r;
            atomicMax(rowmax + grow, fenc(v));
          }
        }
      }
#pragma unroll
      for (int n = 0; n < 4; ++n) {
        float cm = -512.0f;
#pragma unroll
        for (int m = 0; m < 4; ++m) {
          cm = fmaxf(cm, acc[m][n][0]);
          cm = fmaxf(cm, acc[m][n][1]);
          cm = fmaxf(cm, acc[m][n][2]);
          cm = fmaxf(cm, acc[m][n][3]);
        }
        cm = fmaxf(cm, __shfl_xor(cm, 16));
        cm = fmaxf(cm, __shfl_xor(cm, 32));
        if (lane < 16) {
          const int gcol = bcol + wc * 64 + n * 16 + lane;
          atomicMax(colmax + gcol, fenc(cm));
        }
      }
#pragma unroll
      for (int m = 0; m < 4; ++m)
#pragma unroll
        for (int n = 0; n < 4; ++n) acc[m][n] = (f32x4){0.f, 0.f, 0.f, 0.f};
    }
  }
}

// ---- entropy: out[b] = -sum( exp(lp)*lp ), x = decoded max / FSCALE^2 ----
// 1024 threads/block, uint4 loads: 2 vector loads + 8 expf per thread
// (was 32 strided scalar loads -> latency chain on a 2-block grid).
__global__ __launch_bounds__(1024) void entropy_kernel(
    const unsigned* __restrict__ enc, float* __restrict__ out) {
  const int which = blockIdx.x;
  const uint4* e4 = (const uint4*)(enc + which * NROWS);  // 2048 uint4
  const int t = threadIdx.x;
  float s = 0.0f;
#pragma unroll
  for (int i = 0; i < 2; ++i) {
    const uint4 v = e4[t + i * 1024];
#pragma unroll
    for (int j = 0; j < 4; ++j) {
      const unsigned uv = (j == 0) ? v.x : (j == 1) ? v.y : (j == 2) ? v.z : v.w;
      const float x = fdec(uv) * INV_FS2;
      const float z = (x - 1.0f) * (1.0f / 0.3f);
      const float lp = -0.5f * z * z + 0.2850342711439819f;
      s += expf(lp) * lp;
    }
  }
#pragma unroll
  for (int m = 1; m <= 32; m <<= 1) s += __shfl_xor(s, m);
  __shared__ float sr[16];
  if ((t & 63) == 0) sr[t >> 6] = s;
  __syncthreads();
  if (t == 0) {
    float tot = 0.f;
#pragma unroll
    for (int i = 0; i < 16; ++i) tot += sr[i];
    out[which] = -tot;
  }
}

extern "C" void kernel_launch(void* const* d_in, const int* in_sizes, int n_in,
                              void* d_out, int out_size, void* d_ws, size_t ws_size,
                              hipStream_t stream) {
  const float* ex = (const float*)d_in[0];
  const float* ey = (const float*)d_in[1];

  u8* Xf = (u8*)d_ws;                                    // 4 MB MX-fragment-major
  u8* Yf = Xf + (size_t)NROWS * DIM;                     // 4 MB
  unsigned* enc = (unsigned*)(Yf + (size_t)NROWS * DIM); // 2*8192 u32
  float* out = (float*)d_out;

  hipLaunchKernelGGL(normf_kernel, dim3(1024), dim3(512), 0, stream,
                     ex, ey, Xf, Yf, enc);
  hipLaunchKernelGGL(gemm_max_kernel, dim3(1024), dim3(256), 0, stream,
                     Xf, Yf, enc, enc + NROWS);
  hipLaunchKernelGGL(entropy_kernel, dim3(2), dim3(1024), 0, stream, enc, out);
}